// Round 6
// baseline (223.464 us; speedup 1.0000x reference)
//
#include <hip/hip_runtime.h>

#define T_DIM 512
#define B_DIM 8192
#define NCH   128                 // time chunks
#define LT    4                   // timesteps per chunk (NCH*LT == T_DIM)
#define CPW   256                 // columns per wave (4 per lane, float4)
#define NCG   (B_DIM / CPW)       // 32 column groups
#define WPB   4                   // waves per block -> 256 threads
#define K_BLOCK 256
#define K_GRID  ((NCH * NCG) / WPB)   // 1024 blocks -> 16 waves/CU
#define GAMMA 0.99f

// Workspace (8 MB + 12 B):
//   SC : float[NCH][B_DIM]  chunk S; overwritten in-place with carry-in @ 0
//   MM : float[NCH][B_DIM]  chunk M                                    @ 4 MB
//   ACC: float[2] + uint ticket                                        @ 8 MB
#define SC_OFF  0
#define MM_OFF  ((size_t)NCH * B_DIM * sizeof(float))
#define ACC_OFF (2 * MM_OFF)

// Identities (RHO_THRESHOLD == C_THRESHOLD == 1):
//   ratio = (p_a*sum_q)/(sum_p*q_a); m = gamma*min(ratio,1)*(1-done)
//   s = v + min(ratio,1)*(r - v); vtrace = s + m*carry; adv = vtrace - v
//   critic = 0.5*mean(adv^2); next_v cancels except the t=T-1 init.
// History: R1/R2 per-t reg arrays -> scratch; R3 LDS -> 1 blk/CU stall;
// R4/R5 recompute pipeline right but 4 B/lane loads + tight VGPR caps ->
// ~1-2 KB in flight per wave -> latency-bound at 1.1-1.6 TB/s.
// R6: float4 per lane (8 KB/wave/iter in flight), 4 indep chains/lane,
// 128-VGPR cap so the scheduler can hoist a full iteration.

__device__ __forceinline__ void col_eval(float p0, float p1, float q0, float q1,
                                         float vv, float rr, int a, int d,
                                         float& ratio, float& m, float& s) {
    float pa = a ? p1 : p0;
    float qa = a ? q1 : q0;
    ratio = (pa * (q0 + q1)) / ((p0 + p1) * qa);
    float rho = fminf(ratio, 1.0f);
    m = d ? 0.0f : GAMMA * rho;
    s = fmaf(rho, rr - vv, vv);
}

__launch_bounds__(K_BLOCK, 4)
__global__ void k_comp(const float* __restrict__ prob,
                       const float* __restrict__ aprob,
                       const float* __restrict__ v,
                       const float* __restrict__ rw,
                       const int* __restrict__ act,
                       const int* __restrict__ dnn,
                       float* __restrict__ SC,
                       float* __restrict__ MM) {
    const int lane = threadIdx.x & 63;
    const int gw   = blockIdx.x * WPB + (threadIdx.x >> 6);
    const int cg   = gw & (NCG - 1);
    const int ch   = gw >> 5;                  // NCG == 32
    const int col4 = cg * 64 + lane;           // float4 index within a row
    const int t0   = ch * LT;

    const float4* __restrict__ prob4  = (const float4*)prob;   // row = 4096 f4
    const float4* __restrict__ aprob4 = (const float4*)aprob;
    const float4* __restrict__ v4     = (const float4*)v;      // row = 2048 f4
    const float4* __restrict__ rw4    = (const float4*)rw;
    const int4*   __restrict__ act4   = (const int4*)act;
    const int4*   __restrict__ dnn4   = (const int4*)dnn;

    float S0 = 0.f, S1 = 0.f, S2 = 0.f, S3 = 0.f;
    float M0 = 1.f, M1 = 1.f, M2 = 1.f, M3 = 1.f;
#pragma unroll
    for (int i = LT - 1; i >= 0; --i) {
        const int t  = t0 + i;
        const int rb = t * (B_DIM / 4) + col4;
        const int pb = t * (B_DIM / 2) + col4 * 2;
        float4 pr0 = prob4[pb],  pr1 = prob4[pb + 1];
        float4 qr0 = aprob4[pb], qr1 = aprob4[pb + 1];
        float4 vv  = v4[rb];
        float4 rr  = rw4[rb];
        int4   aa  = act4[rb];
        int4   dd  = dnn4[rb];
        float ratio, m, s;
        col_eval(pr0.x, pr0.y, qr0.x, qr0.y, vv.x, rr.x, aa.x, dd.x, ratio, m, s);
        S0 = fmaf(m, S0, s); M0 *= m;
        col_eval(pr0.z, pr0.w, qr0.z, qr0.w, vv.y, rr.y, aa.y, dd.y, ratio, m, s);
        S1 = fmaf(m, S1, s); M1 *= m;
        col_eval(pr1.x, pr1.y, qr1.x, qr1.y, vv.z, rr.z, aa.z, dd.z, ratio, m, s);
        S2 = fmaf(m, S2, s); M2 *= m;
        col_eval(pr1.z, pr1.w, qr1.z, qr1.w, vv.w, rr.w, aa.w, dd.w, ratio, m, s);
        S3 = fmaf(m, S3, s); M3 *= m;
    }
    float4* SC4 = (float4*)SC;
    float4* MM4 = (float4*)MM;
    SC4[ch * (B_DIM / 4) + col4] = make_float4(S0, S1, S2, S3);
    MM4[ch * (B_DIM / 4) + col4] = make_float4(M0, M1, M2, M3);
}

// Cross-chunk suffix scan per column; overwrites SC[ch] with carry ENTERING
// chunk ch. Loads are address-independent of the carry -> prefetchable.
__global__ void k_scan(float* __restrict__ SC,
                       const float* __restrict__ MM,
                       const float* __restrict__ nv) {
    const int col = blockIdx.x * blockDim.x + threadIdx.x;   // 8192 threads
    float carry = nv[(T_DIM - 1) * B_DIM + col];
#pragma unroll 16
    for (int ch = NCH - 1; ch >= 0; --ch) {
        float s = SC[ch * B_DIM + col];
        float m = MM[ch * B_DIM + col];
        SC[ch * B_DIM + col] = carry;
        carry = fmaf(m, carry, s);
    }
}

__launch_bounds__(K_BLOCK, 4)
__global__ void k_replay(const float* __restrict__ prob,
                         const float* __restrict__ aprob,
                         const float* __restrict__ v,
                         const float* __restrict__ rw,
                         const int* __restrict__ act,
                         const int* __restrict__ dnn,
                         const float* __restrict__ CIN,   // == SC after scan
                         float* __restrict__ ACC,
                         float* __restrict__ out) {
    __shared__ float red[2 * WPB];
    const int lane = threadIdx.x & 63;
    const int wv   = threadIdx.x >> 6;
    const int gw   = blockIdx.x * WPB + wv;
    const int cg   = gw & (NCG - 1);
    const int ch   = gw >> 5;
    const int col4 = cg * 64 + lane;
    const int t0   = ch * LT;

    const float4* __restrict__ prob4  = (const float4*)prob;
    const float4* __restrict__ aprob4 = (const float4*)aprob;
    const float4* __restrict__ v4     = (const float4*)v;
    const float4* __restrict__ rw4    = (const float4*)rw;
    const int4*   __restrict__ act4   = (const int4*)act;
    const int4*   __restrict__ dnn4   = (const int4*)dnn;
    const float4* __restrict__ cin4   = (const float4*)CIN;

    float4 cc = cin4[ch * (B_DIM / 4) + col4];
    float c0 = cc.x, c1 = cc.y, c2 = cc.z, c3 = cc.w;
    float critic = 0.0f, msum = 0.0f;
#pragma unroll
    for (int i = LT - 1; i >= 0; --i) {
        const int t  = t0 + i;
        const int rb = t * (B_DIM / 4) + col4;
        const int pb = t * (B_DIM / 2) + col4 * 2;
        float4 pr0 = prob4[pb],  pr1 = prob4[pb + 1];
        float4 qr0 = aprob4[pb], qr1 = aprob4[pb + 1];
        float4 vv  = v4[rb];
        float4 rr  = rw4[rb];
        int4   aa  = act4[rb];
        int4   dd  = dnn4[rb];
        float ratio, m, s, u, adv, rc;

        col_eval(pr0.x, pr0.y, qr0.x, qr0.y, vv.x, rr.x, aa.x, dd.x, ratio, m, s);
        u = fmaf(m, c0, s); adv = u - vv.x; c0 = u;
        critic = fmaf(adv, adv, critic);
        rc = fminf(fmaxf(ratio, 0.8f), 1.2f);
        msum += fminf(ratio * adv, rc * adv);

        col_eval(pr0.z, pr0.w, qr0.z, qr0.w, vv.y, rr.y, aa.y, dd.y, ratio, m, s);
        u = fmaf(m, c1, s); adv = u - vv.y; c1 = u;
        critic = fmaf(adv, adv, critic);
        rc = fminf(fmaxf(ratio, 0.8f), 1.2f);
        msum += fminf(ratio * adv, rc * adv);

        col_eval(pr1.x, pr1.y, qr1.x, qr1.y, vv.z, rr.z, aa.z, dd.z, ratio, m, s);
        u = fmaf(m, c2, s); adv = u - vv.z; c2 = u;
        critic = fmaf(adv, adv, critic);
        rc = fminf(fmaxf(ratio, 0.8f), 1.2f);
        msum += fminf(ratio * adv, rc * adv);

        col_eval(pr1.z, pr1.w, qr1.z, qr1.w, vv.w, rr.w, aa.w, dd.w, ratio, m, s);
        u = fmaf(m, c3, s); adv = u - vv.w; c3 = u;
        critic = fmaf(adv, adv, critic);
        rc = fminf(fmaxf(ratio, 0.8f), 1.2f);
        msum += fminf(ratio * adv, rc * adv);
    }

    // wave reduce, then cross-wave via LDS
#pragma unroll
    for (int off = 32; off > 0; off >>= 1) {
        critic += __shfl_down(critic, off, 64);
        msum   += __shfl_down(msum, off, 64);
    }
    if (lane == 0) { red[wv] = critic; red[WPB + wv] = msum; }
    __syncthreads();
    if (threadIdx.x == 0) {
        float cs = red[0] + red[1] + red[2] + red[3];
        float ms = red[WPB] + red[WPB + 1] + red[WPB + 2] + red[WPB + 3];
        atomicAdd(&ACC[0], cs);
        atomicAdd(&ACC[1], ms);
        __threadfence();
        unsigned* cnt = (unsigned*)(ACC + 2);
        if (atomicAdd(cnt, 1u) == K_GRID - 1) {
            __threadfence();
            float c_tot = atomicAdd(&ACC[0], 0.0f);
            float m_tot = atomicAdd(&ACC[1], 0.0f);
            const float invN = 1.0f / (float)((size_t)T_DIM * B_DIM);
            out[0] = 0.5f * c_tot * invN - m_tot * invN;
        }
    }
}

extern "C" void kernel_launch(void* const* d_in, const int* in_sizes, int n_in,
                              void* d_out, int out_size, void* d_ws, size_t ws_size,
                              hipStream_t stream) {
    const float* prob  = (const float*)d_in[0];
    const float* aprob = (const float*)d_in[1];
    const float* v     = (const float*)d_in[2];
    const float* nv    = (const float*)d_in[3];
    const float* rw    = (const float*)d_in[4];
    const int*   act   = (const int*)d_in[5];
    const int*   dnn   = (const int*)d_in[6];

    float* SC  = (float*)((char*)d_ws + SC_OFF);
    float* MM  = (float*)((char*)d_ws + MM_OFF);
    float* ACC = (float*)((char*)d_ws + ACC_OFF);
    float* out = (float*)d_out;

    hipMemsetAsync(ACC, 0, 12, stream);
    k_comp<<<K_GRID, K_BLOCK, 0, stream>>>(prob, aprob, v, rw, act, dnn, SC, MM);
    k_scan<<<B_DIM / 256, 256, 0, stream>>>(SC, MM, nv);
    k_replay<<<K_GRID, K_BLOCK, 0, stream>>>(prob, aprob, v, rw, act, dnn,
                                             SC, ACC, out);
}